// Round 1
// baseline (317.656 us; speedup 1.0000x reference)
//
#include <hip/hip_runtime.h>
#include <math.h>

#define NC 722
#define NROWS 65536
#define ROWS_PER_BLOCK 32
#define ROWS_PER_WAVE 8

__global__ void init_out_kernel(float* out) {
    if (threadIdx.x == 0) out[0] = 0.0f;
}

__global__ __launch_bounds__(256) void ce_gauss_kernel(
        const float* __restrict__ pred,
        const int* __restrict__ target,
        float* __restrict__ out) {
    const int lane = threadIdx.x & 63;
    const int wave = threadIdx.x >> 6;
    __shared__ float wave_sums[4];

    float acc = 0.0f;
    const int row0 = blockIdx.x * ROWS_PER_BLOCK + wave * ROWS_PER_WAVE;

    for (int r = row0; r < row0 + ROWS_PER_WAVE; ++r) {
        const float* __restrict__ p = pred + (size_t)r * NC;

        // Strided coalesced pass: sum of exp over the row.
        float se = 0.0f;
        for (int i = lane; i < NC; i += 64) {
            se += __expf(p[i]);
        }
        // Wave-wide butterfly reduction (64 lanes).
        #pragma unroll
        for (int off = 32; off > 0; off >>= 1) {
            se += __shfl_xor(se, off, 64);
        }

        if (lane == 0) {
            const int t = target[r];
            // Simulate the reference scatter with overwrite semantics.
            // Slots j=0..6 correspond to class index (t-3+j); all clipped
            // writes land inside this window.
            float w[7] = {0.f, 0.f, 0.f, 0.f, 0.f, 0.f, 0.f};
            const float dec[4] = {0.778800783071f,   // exp(-1/4)
                                  0.606530659713f,   // exp(-1/2)
                                  0.367879441171f,   // exp(-1)
                                  0.135335283237f};  // exp(-2)
            #pragma unroll
            for (int dist = 3; dist >= 1; --dist) {
                int ip = t + dist; if (ip > NC - 1) ip = NC - 1;
                int im = t - dist; if (im < 0) im = 0;
                w[ip - t + 3] = dec[dist];  // direction +1 first
                w[im - t + 3] = dec[dist];  // then -1 (overwrites)
            }
            w[3] = 1.0f;  // dist-0 writes then exact-target set -> 1.0

            float sumw = 0.0f, dot = 0.0f;
            #pragma unroll
            for (int j = 0; j < 7; ++j) {
                if (w[j] > 0.0f) {
                    sumw += w[j];
                    dot += w[j] * p[t - 3 + j];  // L1-hot reload
                }
            }
            acc += sumw * __logf(se) - dot;
        }
    }

    if (lane == 0) wave_sums[wave] = acc;
    __syncthreads();
    if (threadIdx.x == 0) {
        float s = wave_sums[0] + wave_sums[1] + wave_sums[2] + wave_sums[3];
        atomicAdd(out, s * (1.0f / (float)NROWS));
    }
}

extern "C" void kernel_launch(void* const* d_in, const int* in_sizes, int n_in,
                              void* d_out, int out_size, void* d_ws, size_t ws_size,
                              hipStream_t stream) {
    const float* pred = (const float*)d_in[0];
    const int* target = (const int*)d_in[1];
    float* out = (float*)d_out;

    init_out_kernel<<<1, 64, 0, stream>>>(out);

    const int grid = NROWS / ROWS_PER_BLOCK;  // 2048 blocks
    ce_gauss_kernel<<<grid, 256, 0, stream>>>(pred, target, out);
}

// Round 3
// 270.460 us; speedup vs baseline: 1.1745x; 1.1745x over previous
//
#include <hip/hip_runtime.h>
#include <math.h>

#define NC 722
#define NF2 361            // float2 per row (722/2), rows are 8B-aligned
#define NROWS 65536
#define ROWS_PER_WAVE 4
#define WAVES_PER_BLOCK 4
#define ROWS_PER_BLOCK (ROWS_PER_WAVE * WAVES_PER_BLOCK)  // 16

__global__ void init_out_kernel(float* out) {
    if (threadIdx.x == 0) out[0] = 0.0f;
}

__global__ __launch_bounds__(256) void ce_gauss_kernel(
        const float* __restrict__ pred,
        const int* __restrict__ target,
        float* __restrict__ out) {
    const int lane = threadIdx.x & 63;
    const int wave = threadIdx.x >> 6;
    __shared__ float wt_lds[WAVES_PER_BLOCK][ROWS_PER_WAVE][8];
    __shared__ float wave_sums[WAVES_PER_BLOCK];

    const int row0 = blockIdx.x * ROWS_PER_BLOCK + wave * ROWS_PER_WAVE;

    // ---- per-row smoothed-label weight tables (all lanes compute; cheap) ----
    // DECAYS[d] = exp(-(2^d)/4): d=0 -> 0.7788, 1 -> 0.6065, 2 -> 0.3679, 3 -> 0.1353
    int   tgt[ROWS_PER_WAVE];
    float sumw[ROWS_PER_WAVE];
    const float DEC1 = 0.606530659713f;  // exp(-1/2), dist 1
    const float DEC2 = 0.367879441171f;  // exp(-1),   dist 2
    const float DEC3 = 0.135335283237f;  // exp(-2),   dist 3
    #pragma unroll
    for (int rr = 0; rr < ROWS_PER_WAVE; ++rr) {
        const int t = target[row0 + rr];
        tgt[rr] = t;
        float w[7] = {0.f, 0.f, 0.f, 0.f, 0.f, 0.f, 0.f};
        // Replay reference scatter: dist = 3..1, direction +1 then -1
        // (later = smaller dist overwrites, incl. clamped collisions).
        #pragma unroll
        for (int dist = 3; dist >= 1; --dist) {
            const float dv = (dist == 3) ? DEC3 : (dist == 2) ? DEC2 : DEC1;
            int ip = t + dist; if (ip > NC - 1) ip = NC - 1;
            int im = t - dist; if (im < 0) im = 0;
            w[ip - t + 3] = dv;
            w[im - t + 3] = dv;
        }
        w[3] = 1.0f;  // dist-0 then exact-target set
        sumw[rr] = w[0] + w[1] + w[2] + w[3] + w[4] + w[5] + w[6];
        if (lane == 0) {
            #pragma unroll
            for (int j = 0; j < 7; ++j) wt_lds[wave][rr][j] = w[j];
        }
    }

    // ---- main pass: 4 rows interleaved, float2 loads, sum of exp ----
    const float2* __restrict__ p2[ROWS_PER_WAVE];
    #pragma unroll
    for (int rr = 0; rr < ROWS_PER_WAVE; ++rr)
        p2[rr] = (const float2*)(pred + (size_t)(row0 + rr) * NC);

    float se[ROWS_PER_WAVE] = {0.f, 0.f, 0.f, 0.f};
    #pragma unroll
    for (int k = 0; k < 6; ++k) {
        const int idx = lane + (k << 6);
        if (idx < NF2) {
            float2 v0 = p2[0][idx];
            float2 v1 = p2[1][idx];
            float2 v2 = p2[2][idx];
            float2 v3 = p2[3][idx];
            se[0] += __expf(v0.x) + __expf(v0.y);
            se[1] += __expf(v1.x) + __expf(v1.y);
            se[2] += __expf(v2.x) + __expf(v2.y);
            se[3] += __expf(v3.x) + __expf(v3.y);
        }
    }
    // Butterfly reduce each row's sum-of-exp across the wave.
    #pragma unroll
    for (int rr = 0; rr < ROWS_PER_WAVE; ++rr) {
        #pragma unroll
        for (int off = 32; off > 0; off >>= 1)
            se[rr] += __shfl_xor(se[rr], off, 64);
    }

    // ---- parallel 7-tap dot: lane = 8*rr + j handles row rr, tap j ----
    float dotv = 0.f;
    const int grr = lane >> 3;   // group = row within wave (0..7)
    const int gj  = lane & 7;    // tap (0..7)
    if (grr < ROWS_PER_WAVE && gj < 7) {
        const float wv = wt_lds[wave][grr][gj];
        if (wv > 0.f) {  // zero weight also masks out-of-range classes
            const int c = tgt[grr] - 3 + gj;
            dotv = wv * pred[(size_t)(row0 + grr) * NC + c];  // L1-hot
        }
    }
    dotv += __shfl_xor(dotv, 1, 64);
    dotv += __shfl_xor(dotv, 2, 64);
    dotv += __shfl_xor(dotv, 4, 64);

    // ---- per-row loss on lane 8*rr, then wave + block reduction ----
    float acc = 0.f;
    if (gj == 0 && grr < ROWS_PER_WAVE)
        acc = sumw[grr] * __logf(se[grr]) - dotv;
    #pragma unroll
    for (int off = 32; off > 0; off >>= 1)
        acc += __shfl_xor(acc, off, 64);

    if (lane == 0) wave_sums[wave] = acc;
    __syncthreads();
    if (threadIdx.x == 0) {
        float s = wave_sums[0] + wave_sums[1] + wave_sums[2] + wave_sums[3];
        atomicAdd(out, s * (1.0f / (float)NROWS));
    }
}

extern "C" void kernel_launch(void* const* d_in, const int* in_sizes, int n_in,
                              void* d_out, int out_size, void* d_ws, size_t ws_size,
                              hipStream_t stream) {
    const float* pred = (const float*)d_in[0];
    const int* target = (const int*)d_in[1];
    float* out = (float*)d_out;

    init_out_kernel<<<1, 64, 0, stream>>>(out);

    const int grid = NROWS / ROWS_PER_BLOCK;  // 4096 blocks
    ce_gauss_kernel<<<grid, 256, 0, stream>>>(pred, target, out);
}